// Round 9
// baseline (181.412 us; speedup 1.0000x reference)
//
#include <hip/hip_runtime.h>

typedef _Float16 half8 __attribute__((ext_vector_type(8)));
typedef float floatx4 __attribute__((ext_vector_type(4)));

#define BB 8
#define CC 64
#define HH 128
#define WW 256
#define DD 64
#define NROW 4            // (b,h) rows per block
#define GRID 256          // 1 block per CU; NROW*GRID == BB*HH
#define OPITCH 260        // Ob row pitch (floats): bank=(4d+w)&31 -> 2 lanes/bank

// LDS-only barrier: all cross-wave data flows through LDS; lgkmcnt(0) is
// sufficient. Prefetch loads and output stores stay in flight across
// barriers; waits are per-thread counted vmcnt at the consuming cvt.
#define BAR() asm volatile("s_waitcnt lgkmcnt(0)\n\ts_barrier" ::: "memory")

// out[b,d,h,w] = (1/64) sum_c L[b,c,h,w] * R[b,c,h,w-d], 0 where w<d.
// Banded Gram via mfma_f32_16x16x32_f16 (d = 64-16u+n-m algebra).
// R11: NROW=4 pipeline: 63.5 -> 58.3us. R12: 2-deep register prefetch:
//     null — outstanding BYTES aren't the cap.
// R13: break L1 set-window aliasing. All 32 chunk-streams of a (b,h) row
//     live at b*8MB + c*128KB + h*1KB: the 128KB stride varies only addr
//     bits >=17, so every chunk maps into the SAME ~16-set L1 window
//     (selected by h&3). ~8 ways/set -> only ~8KB of misses can pend per
//     CU; the rest stall at issue => the measured ~9 GB/s/CU plateau.
//     Old mapping (bh = bid + k*256) kept h CONSTANT across a block's 4
//     rows (and R6's CU pairing gave both blocks the same h&127!), so
//     even prefetch aliased the same window. New mapping bh = bid*4 + k:
//     consecutive h per k -> h&3 cycles -> current row drain + k+1 + k+2
//     prefetches each occupy a DIFFERENT set window (~3x pending-miss
//     capacity). Bijective; b constant per block; all else = R12.
__global__ __launch_bounds__(512, 2)
void corr_volume_mfma(const float* __restrict__ left,
                      const float* __restrict__ right,
                      float* __restrict__ out) {
    // 72 KiB arena: phase 1 = Lb[256*64] (32K) + Rb[320*64] (40K) halves;
    // phase 2 (epilogue) overlays Ob[64][OPITCH] floats (66,560 B).
    __shared__ alignas(16) unsigned char smem[73728];
    _Float16* const Lb = (_Float16*)smem;
    _Float16* const Rb = (_Float16*)(smem + 32768);
    float*    const Ob = (float*)smem;

    const int tid  = threadIdx.x;
    const int lane = tid & 63;
    const int wv   = tid >> 6;          // wave 0..7
    const int sw   = lane * 4;          // staged w rows sw..sw+3
    const int cg   = wv;                // staged channel group cg*8..cg*8+7

    const size_t chanStride = (size_t)HH * WW;      // 32768

    float4 lv[2][8], rv[2][8];          // 2-deep prefetch sets (static idx)

    // Prologue: issue rows 0 and 1 (32 loads/thread in flight, 2 windows).
    #pragma unroll
    for (int p = 0; p < 2; ++p) {
        const int bh = blockIdx.x * NROW + p;
        const size_t rowBase = (size_t)(bh >> 7) * CC * chanStride
                             + (size_t)(bh & 127) * WW;
        const float* lp = left  + rowBase + (size_t)(cg * 8) * chanStride + sw;
        const float* rp = right + rowBase + (size_t)(cg * 8) * chanStride + sw;
        #pragma unroll
        for (int c = 0; c < 8; ++c)
            lv[p][c] = *(const float4*)(lp + (size_t)c * chanStride);
        #pragma unroll
        for (int c = 0; c < 8; ++c)
            rv[p][c] = *(const float4*)(rp + (size_t)c * chanStride);
    }

    const int n = lane & 15;            // MFMA col (w) / A row
    const int q = lane >> 4;            // quad
    const int wbase = wv * 32;          // this wave's w range
    const float scale = 1.0f / 64.0f;

    #pragma unroll
    for (int k = 0; k < NROW; ++k) {
        const int p = k & 1;            // compile-time after unroll
        const int bh = blockIdx.x * NROW + k;
        const int b  = bh >> 7;
        const int h  = bh & 127;

        BAR();   // A: prior row's Ob ds_reads done (k=0: orders nothing)

        // Re-zero the w'<0 pad rows (Ob overlay clobbers them every row).
        {
            half8 z = {0, 0, 0, 0, 0, 0, 0, 0};
            *(half8*)&Rb[tid * 8] = z;
        }

        // Transpose 8c x 4w from regs -> LDS. Counted vmcnt wait lands
        // here (set p only; the other set's 16 loads stay in flight).
        {
            #pragma unroll
            for (int s = 0; s < 4; ++s) {
                const int w   = sw + s;
                const int col = (cg ^ (w & 7)) * 8;
                half8 lh, rh;
                #pragma unroll
                for (int c = 0; c < 8; ++c) {
                    lh[c] = (_Float16)((const float*)&lv[p][c])[s];
                    rh[c] = (_Float16)((const float*)&rv[p][c])[s];
                }
                *(half8*)&Lb[w * 64 + col]        = lh;
                *(half8*)&Rb[(w + 64) * 64 + col] = rh;
            }
        }

        // Refill set p with row k+2 — L half pre-BAR (regs just freed).
        const float* lp2 = nullptr;
        const float* rp2 = nullptr;
        if (k + 2 < NROW) {
            const int bh2 = blockIdx.x * NROW + (k + 2);
            const size_t rowBase2 = (size_t)(bh2 >> 7) * CC * chanStride
                                  + (size_t)(bh2 & 127) * WW;
            lp2 = left  + rowBase2 + (size_t)(cg * 8) * chanStride + sw;
            rp2 = right + rowBase2 + (size_t)(cg * 8) * chanStride + sw;
            #pragma unroll
            for (int c = 0; c < 8; ++c)
                lv[p][c] = *(const float4*)(lp2 + (size_t)c * chanStride);
        }

        BAR();   // B: tiles staged (lgkmcnt-only; loads stay in flight)

        // Refill set p, R half — spread issue across the phase.
        if (k + 2 < NROW) {
            #pragma unroll
            for (int c = 0; c < 8; ++c)
                rv[p][c] = *(const float4*)(rp2 + (size_t)c * chanStride);
        }

        // ---------------- MFMA ----------------
        floatx4 acc[2][5];
        #pragma unroll
        for (int t = 0; t < 2; ++t)
            #pragma unroll
            for (int u = 0; u < 5; ++u)
                #pragma unroll
                for (int r = 0; r < 4; ++r)
                    acc[t][u][r] = 0.0f;

        #pragma unroll
        for (int kk = 0; kk < 2; ++kk) {
            const int col = ((kk * 4 + q) ^ (n & 7)) * 8;
            half8 bfrag[2], afrag[6];
            #pragma unroll
            for (int t = 0; t < 2; ++t)
                bfrag[t] = *(const half8*)&Lb[(wbase + t * 16 + n) * 64 + col];
            #pragma unroll
            for (int a = 0; a < 6; ++a)
                afrag[a] = *(const half8*)&Rb[(wbase + a * 16 + n) * 64 + col];
            #pragma unroll
            for (int t = 0; t < 2; ++t)
                #pragma unroll
                for (int u = 0; u < 5; ++u)
                    acc[t][u] = __builtin_amdgcn_mfma_f32_16x16x32_f16(
                        afrag[t + u], bfrag[t], acc[t][u], 0, 0, 0);
        }
        BAR();   // C: all waves' fragment reads done; Lb/Rb dead

        // acc -> Ob[d][w]. C/D: col = n (w), row m = q*4+r. d = 64-16u+n-m.
        // bank = (4d+w)&31: all 32 banks, 2 lanes each.
        #pragma unroll
        for (int t = 0; t < 2; ++t) {
            const int w = wbase + t * 16 + n;
            #pragma unroll
            for (int u = 0; u < 5; ++u) {
                #pragma unroll
                for (int r = 0; r < 4; ++r) {
                    const int d = 64 - 16 * u + n - (q * 4 + r);
                    if (d >= 0 && d < DD) {
                        Ob[d * OPITCH + w] = acc[t][u][r] * scale;
                    }
                }
            }
        }
        BAR();   // D: Ob complete (lgkmcnt-only)

        // Coalesced nontemporal stores: wave wv owns d = wv*8..wv*8+7; each
        // instruction writes one full 1KB row. Stores drain lazily under
        // the next row's phases.
        #pragma unroll
        for (int i = 0; i < 8; ++i) {
            const int d = wv * 8 + i;
            const floatx4 v = *(const floatx4*)&Ob[d * OPITCH + lane * 4];
            floatx4* dst = (floatx4*)&out[(((size_t)b * DD + d) * HH + h) * WW + lane * 4];
            __builtin_nontemporal_store(v, dst);
        }
    }
}

extern "C" void kernel_launch(void* const* d_in, const int* in_sizes, int n_in,
                              void* d_out, int out_size, void* d_ws, size_t ws_size,
                              hipStream_t stream) {
    const float* left  = (const float*)d_in[0];
    const float* right = (const float*)d_in[1];
    float* out = (float*)d_out;

    dim3 grid(GRID);    // 256 blocks = 1 per CU, each pipelines NROW rows
    dim3 block(512);
    corr_volume_mfma<<<grid, block, 0, stream>>>(left, right, out);
}

// Round 10
// 171.662 us; speedup vs baseline: 1.0568x; 1.0568x over previous
//
#include <hip/hip_runtime.h>

typedef _Float16 half8 __attribute__((ext_vector_type(8)));
typedef float floatx4 __attribute__((ext_vector_type(4)));

#define BB 8
#define CC 64
#define HH 128
#define WW 256
#define DD 64
#define NROW 4            // (b,h) rows per block
#define GRID 256          // 1 block per CU; NROW*GRID == BB*HH
#define OPITCH 260        // Ob row pitch (floats): bank=(4d+w)&31 -> 2 lanes/bank

// LDS-only barrier: all cross-wave data flows through LDS; lgkmcnt(0) is
// sufficient. Prefetch loads and output stores stay in flight across
// barriers; waits are per-thread counted vmcnt at the consuming cvt.
#define BAR() asm volatile("s_waitcnt lgkmcnt(0)\n\ts_barrier" ::: "memory")

// out[b,d,h,w] = (1/64) sum_c L[b,c,h,w] * R[b,c,h,w-d], 0 where w<d.
// Banded Gram via mfma_f32_16x16x32_f16 (d = 64-16u+n-m algebra).
// R11 (best, 58.3us): NROW=4 pipeline, lgkm-only barriers, split L/R issue,
//     NT stores, bh = bid + k*GRID (concentrated per-phase footprint).
// R12 (2-deep prefetch): null — VGPR 124 meant the compiler couldn't hold
//     the depth anyway. R13 (h-remap bh=bid*4+k): REGRESSED 59->70us —
//     spreading the chip's instantaneous footprint across all of b hurts
//     DRAM/LLC locality; per-phase 32MB b-slice concentration matters.
// R14: revert to exact R11 + one notch more of R11's proven lever (issue
//     smoothing): the 16-chunk refill is split into 4 groups of 4, issued
//     at 4 distinct points of the row phase (after cvt / pre-BAR B /
//     post-BAR B / post-MFMA). Same depth, smoother per-CU demand.
__global__ __launch_bounds__(512, 2)
void corr_volume_mfma(const float* __restrict__ left,
                      const float* __restrict__ right,
                      float* __restrict__ out) {
    // 72 KiB arena: phase 1 = Lb[256*64] (32K) + Rb[320*64] (40K) halves;
    // phase 2 (epilogue) overlays Ob[64][OPITCH] floats (66,560 B).
    __shared__ alignas(16) unsigned char smem[73728];
    _Float16* const Lb = (_Float16*)smem;
    _Float16* const Rb = (_Float16*)(smem + 32768);
    float*    const Ob = (float*)smem;

    const int tid  = threadIdx.x;
    const int lane = tid & 63;
    const int wv   = tid >> 6;          // wave 0..7
    const int sw   = lane * 4;          // staged w rows sw..sw+3
    const int cg   = wv;                // staged channel group cg*8..cg*8+7

    const size_t chanStride = (size_t)HH * WW;      // 32768

    float4 lv[8], rv[8];

    // Prologue: issue row-0 loads immediately.
    {
        const int bh = blockIdx.x;
        const size_t rowBase = (size_t)(bh >> 7) * CC * chanStride
                             + (size_t)(bh & 127) * WW;
        const float* lp = left  + rowBase + (size_t)(cg * 8) * chanStride + sw;
        const float* rp = right + rowBase + (size_t)(cg * 8) * chanStride + sw;
        #pragma unroll
        for (int c = 0; c < 8; ++c) {
            lv[c] = *(const float4*)(lp + (size_t)c * chanStride);
            rv[c] = *(const float4*)(rp + (size_t)c * chanStride);
        }
    }

    const int n = lane & 15;            // MFMA col (w) / A row
    const int q = lane >> 4;            // quad
    const int wbase = wv * 32;          // this wave's w range
    const float scale = 1.0f / 64.0f;

    #pragma unroll
    for (int k = 0; k < NROW; ++k) {
        const int bh = blockIdx.x + k * GRID;
        const int b  = bh >> 7;
        const int h  = bh & 127;

        BAR();   // A: prior row's Ob ds_reads done (k=0: orders nothing)

        // Re-zero the w'<0 pad rows (Ob overlay clobbers them every row).
        {
            half8 z = {0, 0, 0, 0, 0, 0, 0, 0};
            *(half8*)&Rb[tid * 8] = z;
        }

        // Transpose 8c x 4w from regs -> LDS. Per-thread counted vmcnt
        // waits for this row's loads happen here; no cross-wave drain.
        {
            const float* lf = (const float*)lv;
            const float* rf = (const float*)rv;
            #pragma unroll
            for (int s = 0; s < 4; ++s) {
                const int w   = sw + s;
                const int col = (cg ^ (w & 7)) * 8;
                half8 lh, rh;
                #pragma unroll
                for (int c = 0; c < 8; ++c) {
                    lh[c] = (_Float16)lf[c * 4 + s];
                    rh[c] = (_Float16)rf[c * 4 + s];
                }
                *(half8*)&Lb[w * 64 + col]        = lh;
                *(half8*)&Rb[(w + 64) * 64 + col] = rh;
            }
        }

        // Refill, group 1 of 4 (L chunks 0-3) — regs just freed by cvt.
        const float* lp2 = nullptr;
        const float* rp2 = nullptr;
        if (k + 1 < NROW) {
            const int bh2 = blockIdx.x + (k + 1) * GRID;
            const size_t rowBase2 = (size_t)(bh2 >> 7) * CC * chanStride
                                  + (size_t)(bh2 & 127) * WW;
            lp2 = left  + rowBase2 + (size_t)(cg * 8) * chanStride + sw;
            rp2 = right + rowBase2 + (size_t)(cg * 8) * chanStride + sw;
            #pragma unroll
            for (int c = 0; c < 4; ++c)
                lv[c] = *(const float4*)(lp2 + (size_t)c * chanStride);
        }

        BAR();   // B: tiles staged (lgkmcnt-only; loads stay in flight)

        // Refill, group 2 of 4 (L chunks 4-7).
        if (k + 1 < NROW) {
            #pragma unroll
            for (int c = 4; c < 8; ++c)
                lv[c] = *(const float4*)(lp2 + (size_t)c * chanStride);
        }

        // ---------------- MFMA ----------------
        floatx4 acc[2][5];
        #pragma unroll
        for (int t = 0; t < 2; ++t)
            #pragma unroll
            for (int u = 0; u < 5; ++u)
                #pragma unroll
                for (int r = 0; r < 4; ++r)
                    acc[t][u][r] = 0.0f;

        #pragma unroll
        for (int kk = 0; kk < 2; ++kk) {
            const int col = ((kk * 4 + q) ^ (n & 7)) * 8;
            half8 bfrag[2], afrag[6];
            #pragma unroll
            for (int t = 0; t < 2; ++t)
                bfrag[t] = *(const half8*)&Lb[(wbase + t * 16 + n) * 64 + col];
            #pragma unroll
            for (int a = 0; a < 6; ++a)
                afrag[a] = *(const half8*)&Rb[(wbase + a * 16 + n) * 64 + col];
            #pragma unroll
            for (int t = 0; t < 2; ++t)
                #pragma unroll
                for (int u = 0; u < 5; ++u)
                    acc[t][u] = __builtin_amdgcn_mfma_f32_16x16x32_f16(
                        afrag[t + u], bfrag[t], acc[t][u], 0, 0, 0);

            // Refill, group 3 of 4 (R chunks 0-3) — between MFMA halves.
            if (kk == 0 && k + 1 < NROW) {
                #pragma unroll
                for (int c = 0; c < 4; ++c)
                    rv[c] = *(const float4*)(rp2 + (size_t)c * chanStride);
            }
        }
        BAR();   // C: all waves' fragment reads done; Lb/Rb dead

        // Refill, group 4 of 4 (R chunks 4-7).
        if (k + 1 < NROW) {
            #pragma unroll
            for (int c = 4; c < 8; ++c)
                rv[c] = *(const float4*)(rp2 + (size_t)c * chanStride);
        }

        // acc -> Ob[d][w]. C/D: col = n (w), row m = q*4+r. d = 64-16u+n-m.
        // bank = (4d+w)&31: all 32 banks, 2 lanes each.
        #pragma unroll
        for (int t = 0; t < 2; ++t) {
            const int w = wbase + t * 16 + n;
            #pragma unroll
            for (int u = 0; u < 5; ++u) {
                #pragma unroll
                for (int r = 0; r < 4; ++r) {
                    const int d = 64 - 16 * u + n - (q * 4 + r);
                    if (d >= 0 && d < DD) {
                        Ob[d * OPITCH + w] = acc[t][u][r] * scale;
                    }
                }
            }
        }
        BAR();   // D: Ob complete (lgkmcnt-only)

        // Coalesced nontemporal stores: wave wv owns d = wv*8..wv*8+7; each
        // instruction writes one full 1KB row. Stores drain lazily under
        // the next row's phases.
        #pragma unroll
        for (int i = 0; i < 8; ++i) {
            const int d = wv * 8 + i;
            const floatx4 v = *(const floatx4*)&Ob[d * OPITCH + lane * 4];
            floatx4* dst = (floatx4*)&out[(((size_t)b * DD + d) * HH + h) * WW + lane * 4];
            __builtin_nontemporal_store(v, dst);
        }
    }
}

extern "C" void kernel_launch(void* const* d_in, const int* in_sizes, int n_in,
                              void* d_out, int out_size, void* d_ws, size_t ws_size,
                              hipStream_t stream) {
    const float* left  = (const float*)d_in[0];
    const float* right = (const float*)d_in[1];
    float* out = (float*)d_out;

    dim3 grid(GRID);    // 256 blocks = 1 per CU, each pipelines NROW rows
    dim3 block(512);
    corr_volume_mfma<<<grid, block, 0, stream>>>(left, right, out);
}